// Round 1
// baseline (224.072 us; speedup 1.0000x reference)
//
#include <hip/hip_runtime.h>
#include <hip/hip_bf16.h>

// CZ gate on a batch of statevectors: out = state * diag(±1), where the
// diagonal is -1 iff basis-index bits c2 and t2 are both set.
// Key fact: D = 2^num_qubits is a power of two, and c2,t2 < num_qubits,
// so bits c2,t2 of the FLAT index equal bits c2,t2 of the column index.
// => sign depends only on the flat element index; no need for D on host.
// Pure streaming op: xor the float's sign bit, 16 B/lane uint4 traffic.

__global__ void __launch_bounds__(256)
cz_kernel(const uint4* __restrict__ in, uint4* __restrict__ out,
          const int* __restrict__ p_ctrl, const int* __restrict__ p_tgt,
          const int* __restrict__ p_nq, long long n4) {
    const int nq = *p_nq;
    const int c2 = nq - *p_ctrl - 1;
    const int t2 = nq - *p_tgt - 1;

    const long long stride = (long long)gridDim.x * blockDim.x;
    for (long long i = (long long)blockIdx.x * blockDim.x + threadIdx.x;
         i < n4; i += stride) {
        uint4 v = in[i];
        const unsigned long long b = (unsigned long long)i * 4ull;
        // per-element mask (handles t2/c2 < 2 correctly, costs ~8 VALU ops)
        unsigned m0 = (unsigned)(((b >> c2) & 1ull) & ((b >> t2) & 1ull)) << 31;
        unsigned m1 = (unsigned)((((b + 1) >> c2) & 1ull) & (((b + 1) >> t2) & 1ull)) << 31;
        unsigned m2 = (unsigned)((((b + 2) >> c2) & 1ull) & (((b + 2) >> t2) & 1ull)) << 31;
        unsigned m3 = (unsigned)((((b + 3) >> c2) & 1ull) & (((b + 3) >> t2) & 1ull)) << 31;
        v.x ^= m0;
        v.y ^= m1;
        v.z ^= m2;
        v.w ^= m3;
        out[i] = v;
    }
}

extern "C" void kernel_launch(void* const* d_in, const int* in_sizes, int n_in,
                              void* d_out, int out_size, void* d_ws, size_t ws_size,
                              hipStream_t stream) {
    const float* state = (const float*)d_in[0];
    const int* p_ctrl  = (const int*)d_in[1];
    const int* p_tgt   = (const int*)d_in[2];
    const int* p_nq    = (const int*)d_in[3];
    float* out = (float*)d_out;

    const long long n  = (long long)in_sizes[0];   // 16384 * 8192, divisible by 4
    const long long n4 = n >> 2;

    const int block = 256;
    // memory-bound streaming: ~8 blocks/CU * 256 CUs, grid-stride the rest
    long long want = (n4 + block - 1) / block;
    int grid = (int)(want < 2048 ? want : 2048);

    cz_kernel<<<grid, block, 0, stream>>>(
        (const uint4*)state, (uint4*)out, p_ctrl, p_tgt, p_nq, n4);
}

// Round 2
// 197.362 us; speedup vs baseline: 1.1353x; 1.1353x over previous
//
#include <hip/hip_runtime.h>
#include <hip/hip_bf16.h>

// CZ gate: out[i] = state[i] with sign flipped iff bits c2,t2 of the flat
// index are both set (D is a power of two, so column-index bits == flat-index
// bits for bit positions < num_qubits). Pure 1 GiB R+W streaming op.
//
// Round-2 changes vs baseline (224 us, 4.79 TB/s):
//  - nontemporal load/store (nt): bypass L2/LIC allocation for dead
//    streaming lines -> target the ~6.3 TB/s copy ceiling.
//  - 32-bit index math (n = 2^27 < 2^32).
//  - fast path for min(c2,t2) >= 2: sign is uniform across a 16B vector,
//    one shift/and/shl per iteration instead of 4x 64-bit chains.

typedef int  v4i __attribute__((ext_vector_type(4)));
typedef unsigned int u32;

__global__ void __launch_bounds__(256)
cz_kernel(const v4i* __restrict__ in, v4i* __restrict__ out,
          const int* __restrict__ p_ctrl, const int* __restrict__ p_tgt,
          const int* __restrict__ p_nq, int n4) {
    const int nq = *p_nq;
    const int c2 = nq - *p_ctrl - 1;
    const int t2 = nq - *p_tgt - 1;

    const int stride = gridDim.x * blockDim.x;
    int i = blockIdx.x * blockDim.x + threadIdx.x;

    if (c2 >= 2 && t2 >= 2) {
        // sign uniform across each aligned group of 4 elements
        for (; i < n4; i += stride) {
            v4i v = __builtin_nontemporal_load(&in[i]);
            const u32 b = (u32)i << 2;
            const int m = (int)((((b >> c2) & (b >> t2)) & 1u) << 31);
            v.x ^= m; v.y ^= m; v.z ^= m; v.w ^= m;
            __builtin_nontemporal_store(v, &out[i]);
        }
    } else {
        // general path: per-element sign
        for (; i < n4; i += stride) {
            v4i v = __builtin_nontemporal_load(&in[i]);
            const u32 b = (u32)i << 2;
            v.x ^= (int)((((b >> c2) & (b >> t2)) & 1u) << 31);
            v.y ^= (int)(((((b + 1) >> c2) & ((b + 1) >> t2)) & 1u) << 31);
            v.z ^= (int)(((((b + 2) >> c2) & ((b + 2) >> t2)) & 1u) << 31);
            v.w ^= (int)(((((b + 3) >> c2) & ((b + 3) >> t2)) & 1u) << 31);
            __builtin_nontemporal_store(v, &out[i]);
        }
    }
}

extern "C" void kernel_launch(void* const* d_in, const int* in_sizes, int n_in,
                              void* d_out, int out_size, void* d_ws, size_t ws_size,
                              hipStream_t stream) {
    const float* state = (const float*)d_in[0];
    const int* p_ctrl  = (const int*)d_in[1];
    const int* p_tgt   = (const int*)d_in[2];
    const int* p_nq    = (const int*)d_in[3];
    float* out = (float*)d_out;

    const long long n = (long long)in_sizes[0];   // 16384 * 8192 = 2^27
    const int n4 = (int)(n >> 2);                 // 2^25, fits int

    const int block = 256;
    long long want = ((long long)n4 + block - 1) / block;
    int grid = (int)(want < 2048 ? want : 2048);  // 8 blocks/CU, grid-stride

    cz_kernel<<<grid, block, 0, stream>>>(
        (const v4i*)state, (v4i*)out, p_ctrl, p_tgt, p_nq, n4);
}